// Round 12
// baseline (173.409 us; speedup 1.0000x reference)
//
#include <hip/hip_runtime.h>
#include <hip/hip_bf16.h>
#include <stdint.h>

// Flash attention B=4,H=8,S=2048,D=64 fp32 io, bf16 MFMA compute.
// Round 12: R11's 32x32x16 layout (verified) with residency fixed:
// single-buffered K+V per key-group -> 33.8 KB LDS -> 3 blocks/CU
// (R11's 64KB dbuf gave 1 block/CU lockstep). 2-barrier epoch; drain
// hidden by co-resident blocks. Split-K merge epilogue verbatim R11.

typedef __bf16 bf16;
typedef __attribute__((ext_vector_type(8))) __bf16 bf16x8;
typedef __attribute__((ext_vector_type(4))) __bf16 bf16x4;
typedef __attribute__((ext_vector_type(4))) float floatx4;
typedef __attribute__((ext_vector_type(16))) float floatx16;

#define SLEN 2048
#define DH   64
#define BR   64
#define BC   64
#define NKT  (SLEN / BC)      // 32 64-key tiles
#define NQT  (SLEN / BR)
#define BH_N 32
#define LOG2E 1.44269504088896341f

#define CHB_L  1024           // LDS chunk stride (8 rows x 128B)
#define IMGE_G 4096           // bf16 elements per image in global (8192 B)

#define AS1 __attribute__((address_space(1)))
#define AS3 __attribute__((address_space(3)))

static __device__ inline void gload_lds16(const void* g, void* l) {
    __builtin_amdgcn_global_load_lds((const AS1 uint32_t*)g, (AS3 uint32_t*)l, 16, 0, 0);
}

static_assert(BH_N == NQT, "prep kernel folds bh and qt onto one grid axis");

// 32x32 PV key relabeling: logical position l (0..63) -> physical key.
// l = 16kc + 8h + j  ->  16kc + 4h + j + 4*(j>>2)
static __device__ inline int phys_key32(int l) {
    int kc = l >> 4, rem = l & 15, h = rem >> 3, j = rem & 7;
    return 16 * kc + 4 * h + j + 4 * (j >> 2);
}

// ---- prepass (R11 verbatim): swizzled K image + V image (phys_key32) ----
__global__ __launch_bounds__(256) void kv_prep(
    const float* __restrict__ kv, const float* __restrict__ mask,
    bf16* __restrict__ kvK, bf16* __restrict__ kvT, int* __restrict__ flags)
{
    __shared__ bf16 Tl[64 * 72];
    __shared__ int wany[4];
    const int kt = blockIdx.x, z = blockIdx.y;   // z = bh for kv, z = qt for mask
    const int t = threadIdx.x;

    float acc = 0.f;
#pragma unroll
    for (int i = 0; i < 4; ++i) {
        int f = i * 256 + t;
        int row = f >> 4, c4 = (f & 15) * 4;
        const float4 v = *(const float4*)(mask + (size_t)(z * BR + row) * SLEN + kt * BC + c4);
        acc = fmaxf(acc, fmaxf(fmaxf(fabsf(v.x), fabsf(v.y)), fmaxf(fabsf(v.z), fabsf(v.w))));
    }
    unsigned long long any = __ballot(acc != 0.f);
    if ((t & 63) == 0) wany[t >> 6] = (any != 0ull) ? 1 : 0;

    const float* src = kv + ((size_t)z * SLEN + kt * BC) * DH;
#pragma unroll
    for (int i = 0; i < 4; ++i) {
        int f = i * 256 + t;
        int key = f >> 4, d4 = (f & 15) * 4;
        float4 v = *(const float4*)(src + (size_t)key * DH + d4);
        bf16x4 b; b[0] = (bf16)v.x; b[1] = (bf16)v.y; b[2] = (bf16)v.z; b[3] = (bf16)v.w;
        *(bf16x4*)&Tl[key * 72 + d4] = b;
    }
    __syncthreads();
    if (t == 0) flags[z * NKT + kt] = wany[0] | wany[1] | wany[2] | wany[3];

    // K image: granule (chunk c, pos p, row rl): g = (p - rl - 4*(c&1)) & 7
    bf16* outK = kvK + ((size_t)z * NKT + kt) * IMGE_G;
#pragma unroll
    for (int i = 0; i < 2; ++i) {
        int G = i * 256 + t;
        int c = G >> 6, L = G & 63, rl = L >> 3, p = L & 7;
        int g = (p - rl - 4 * (c & 1)) & 7, key = 8 * c + rl;
        bf16x8 w = *(const bf16x8*)&Tl[key * 72 + g * 8];
        *(bf16x8*)(outK + (size_t)G * 8) = w;
    }
    // V image: rows = d; content = logical keys 8g..8g+7 gathered via phys_key32
    bf16* outV = kvT + ((size_t)z * NKT + kt) * IMGE_G;
#pragma unroll
    for (int i = 0; i < 2; ++i) {
        int G = i * 256 + t;
        int c = G >> 6, L = G & 63, dl = L >> 3, p = L & 7;
        int g = (p - dl - 4 * (c & 1)) & 7, d = 8 * c + dl;
        bf16x8 w;
#pragma unroll
        for (int j = 0; j < 8; ++j)
            w[j] = Tl[phys_key32(8 * g + j) * 72 + d];
        *(bf16x8*)(outV + (size_t)G * 8) = w;
    }
}

// ---- main fused attention: 32x32x16, split-K, single-buffered LDS ----
__global__ __launch_bounds__(512) void attn_fwd12(
    const float* __restrict__ q, const float* __restrict__ mask,
    const int* __restrict__ flags,
    const bf16* __restrict__ kvK, const bf16* __restrict__ kvT,
    float* __restrict__ out)
{
    // [group][K 8KB | V 8KB] = 32 KB staging; +1 KB merge (m,l); Xo overlays staging
    __shared__ __align__(16) char smem[33792];

    const int bh = blockIdx.x;
    const int qt = blockIdx.y;          // 128-row q tile
    const int q0 = qt * 128;
    const int t = threadIdx.x;
    const int wave = t >> 6, lane = t & 63;   // wave in [0,8)
    const int grp = wave >> 2;          // key half
    const int w4 = wave & 3;            // 32-row q sub-tile
    const int l31 = lane & 31, h = lane >> 5;

    // lane-constant LDS addressing (same swizzled image as R8/R11)
    const int laneRow = (l31 >> 3) * 1024 + (l31 & 7) * 128;
    const int c0 = (l31 & 7) + 4 * ((l31 >> 3) & 1) + h;
    const int pos0 = ((0 + c0) & 7) * 16;
    const int pos1 = ((2 + c0) & 7) * 16;
    const int pos2 = ((4 + c0) & 7) * 16;
    const int pos3 = ((6 + c0) & 7) * 16;

    // Q B-fragments: B[k=16kc+8h+j][n=qrow=l31], scale folded
    const float qscale = 0.125f * LOG2E;
    bf16x8 aq[4];
    {
        const float* qrow = q + ((size_t)bh * SLEN + q0 + w4 * 32 + l31) * DH;
#pragma unroll
        for (int kc = 0; kc < 4; ++kc) {
            int d0 = 16 * kc + 8 * h;
            float4 f0 = *(const float4*)(qrow + d0);
            float4 f1 = *(const float4*)(qrow + d0 + 4);
            bf16x8 a;
            a[0] = (bf16)(f0.x * qscale); a[1] = (bf16)(f0.y * qscale);
            a[2] = (bf16)(f0.z * qscale); a[3] = (bf16)(f0.w * qscale);
            a[4] = (bf16)(f1.x * qscale); a[5] = (bf16)(f1.y * qscale);
            a[6] = (bf16)(f1.z * qscale); a[7] = (bf16)(f1.w * qscale);
            aq[kc] = a;
        }
    }

    // flag bitmask: this wave's rows live in 64-row flag tile fqt
    const int fqt = qt * 2 + (w4 >> 1);
    unsigned fmask;
    {
        int ld = (lane < 32) ? flags[fqt * NKT + lane] : 0;
        fmask = (unsigned)__ballot(ld != 0);
    }

    floatx16 o0, o1;
#pragma unroll
    for (int i = 0; i < 16; ++i) { o0[i] = 0.f; o1[i] = 0.f; }
    float m_run = -3.0e38f, l_run = 0.f;

    const bf16* kvKb = kvK + (size_t)bh * NKT * IMGE_G;
    const bf16* kvTb = kvT + (size_t)bh * NKT * IMGE_G;
    const int kt0 = grp * (NKT / 2);
    char* Gb = smem + grp * 16384;      // group staging: K at +0, V at +8192

    // prologue: stage tile kt0 (each of 4 waves: 2 K chunks + 2 V chunks)
    {
        const bf16* sK = kvKb + (size_t)kt0 * IMGE_G;
        const bf16* sV = kvTb + (size_t)kt0 * IMGE_G;
        gload_lds16(sK + (size_t)(2 * w4) * 512 + lane * 8,     Gb + (2 * w4) * CHB_L);
        gload_lds16(sK + (size_t)(2 * w4 + 1) * 512 + lane * 8, Gb + (2 * w4 + 1) * CHB_L);
        gload_lds16(sV + (size_t)(2 * w4) * 512 + lane * 8,     Gb + 8192 + (2 * w4) * CHB_L);
        gload_lds16(sV + (size_t)(2 * w4 + 1) * 512 + lane * 8, Gb + 8192 + (2 * w4 + 1) * CHB_L);
    }

    for (int e = 0; e < NKT / 2; ++e) {
        __syncthreads();   // drains vmcnt -> buffer ready
        const int kt = kt0 + e;
        const char* Kb = Gb;
        const char* Vb = Gb + 8192;

        // S^T = K * Q^T : D[m=key][n=qrow=l31]; s0 keys 0..31, s1 keys 32..63
        floatx16 s0, s1;
#pragma unroll
        for (int i = 0; i < 16; ++i) { s0[i] = 0.f; s1[i] = 0.f; }
        {
            bf16x8 k00 = *(const bf16x8*)(Kb + laneRow + pos0);
            bf16x8 k10 = *(const bf16x8*)(Kb + 4096 + laneRow + pos0);
            s0 = __builtin_amdgcn_mfma_f32_32x32x16_bf16(k00, aq[0], s0, 0, 0, 0);
            s1 = __builtin_amdgcn_mfma_f32_32x32x16_bf16(k10, aq[0], s1, 0, 0, 0);
            bf16x8 k01 = *(const bf16x8*)(Kb + laneRow + pos1);
            bf16x8 k11 = *(const bf16x8*)(Kb + 4096 + laneRow + pos1);
            s0 = __builtin_amdgcn_mfma_f32_32x32x16_bf16(k01, aq[1], s0, 0, 0, 0);
            s1 = __builtin_amdgcn_mfma_f32_32x32x16_bf16(k11, aq[1], s1, 0, 0, 0);
            bf16x8 k02 = *(const bf16x8*)(Kb + laneRow + pos2);
            bf16x8 k12 = *(const bf16x8*)(Kb + 4096 + laneRow + pos2);
            s0 = __builtin_amdgcn_mfma_f32_32x32x16_bf16(k02, aq[2], s0, 0, 0, 0);
            s1 = __builtin_amdgcn_mfma_f32_32x32x16_bf16(k12, aq[2], s1, 0, 0, 0);
            bf16x8 k03 = *(const bf16x8*)(Kb + laneRow + pos3);
            bf16x8 k13 = *(const bf16x8*)(Kb + 4096 + laneRow + pos3);
            s0 = __builtin_amdgcn_mfma_f32_32x32x16_bf16(k03, aq[3], s0, 0, 0, 0);
            s1 = __builtin_amdgcn_mfma_f32_32x32x16_bf16(k13, aq[3], s1, 0, 0, 0);
        }

        // mask add (rare): key = 32mb + (r&3)+8(r>>2)+4h
        if (fmask & (1u << kt)) {
            const float* mrow = mask + (size_t)(q0 + w4 * 32 + l31) * SLEN + kt * BC;
#pragma unroll
            for (int r = 0; r < 16; ++r) {
                int key = (r & 3) + 8 * (r >> 2) + 4 * h;
                s0[r] += mrow[key] * LOG2E;
                s1[r] += mrow[32 + key] * LOG2E;
            }
        }

        // lane-local softmax: all 32 scores belong to q-row l31
        float tmax = s0[0];
#pragma unroll
        for (int r = 1; r < 16; ++r) tmax = fmaxf(tmax, s0[r]);
#pragma unroll
        for (int r = 0; r < 16; ++r) tmax = fmaxf(tmax, s1[r]);
        tmax = fmaxf(tmax, __shfl_xor(tmax, 32));
        float mnew = fmaxf(m_run, tmax);
        unsigned long long grew = __ballot(mnew > m_run);
        float alpha = exp2f(m_run - mnew);
        m_run = mnew;

        // p = exp2(s - m); pf[kc] is directly the PV A-fragment for key chunk kc
        float rs = 0.f;
        bf16x8 pf[4];
#pragma unroll
        for (int kcb = 0; kcb < 2; ++kcb) {
#pragma unroll
            for (int j = 0; j < 8; ++j) {
                float p0 = exp2f(s0[8 * kcb + j] - mnew);
                float p1 = exp2f(s1[8 * kcb + j] - mnew);
                rs += p0 + p1;
                pf[kcb][j] = (bf16)p0;
                pf[2 + kcb][j] = (bf16)p1;
            }
        }
        rs += __shfl_xor(rs, 32);

        if (grew) {
            l_run = l_run * alpha + rs;
#pragma unroll
            for (int r = 0; r < 16; ++r) {
                int R = (r & 3) + 8 * (r >> 2) + 4 * h;
                float ar = __shfl(alpha, R);
                o0[r] *= ar; o1[r] *= ar;
            }
        } else {
            l_run += rs;
        }

        // O += P V : o0 cols 0..31, o1 cols 32..63
        {
            bf16x8 v00 = *(const bf16x8*)(Vb + laneRow + pos0);
            bf16x8 v10 = *(const bf16x8*)(Vb + 4096 + laneRow + pos0);
            o0 = __builtin_amdgcn_mfma_f32_32x32x16_bf16(pf[0], v00, o0, 0, 0, 0);
            o1 = __builtin_amdgcn_mfma_f32_32x32x16_bf16(pf[0], v10, o1, 0, 0, 0);
            bf16x8 v01 = *(const bf16x8*)(Vb + laneRow + pos1);
            bf16x8 v11 = *(const bf16x8*)(Vb + 4096 + laneRow + pos1);
            o0 = __builtin_amdgcn_mfma_f32_32x32x16_bf16(pf[1], v01, o0, 0, 0, 0);
            o1 = __builtin_amdgcn_mfma_f32_32x32x16_bf16(pf[1], v11, o1, 0, 0, 0);
            bf16x8 v02 = *(const bf16x8*)(Vb + laneRow + pos2);
            bf16x8 v12 = *(const bf16x8*)(Vb + 4096 + laneRow + pos2);
            o0 = __builtin_amdgcn_mfma_f32_32x32x16_bf16(pf[2], v02, o0, 0, 0, 0);
            o1 = __builtin_amdgcn_mfma_f32_32x32x16_bf16(pf[2], v12, o1, 0, 0, 0);
            bf16x8 v03 = *(const bf16x8*)(Vb + laneRow + pos3);
            bf16x8 v13 = *(const bf16x8*)(Vb + 4096 + laneRow + pos3);
            o0 = __builtin_amdgcn_mfma_f32_32x32x16_bf16(pf[3], v03, o0, 0, 0, 0);
            o1 = __builtin_amdgcn_mfma_f32_32x32x16_bf16(pf[3], v13, o1, 0, 0, 0);
        }

        if (e + 1 < NKT / 2) {   // all waves done reading -> restage buffer
            __syncthreads();
            const bf16* sK = kvKb + (size_t)(kt + 1) * IMGE_G;
            const bf16* sV = kvTb + (size_t)(kt + 1) * IMGE_G;
            gload_lds16(sK + (size_t)(2 * w4) * 512 + lane * 8,     Gb + (2 * w4) * CHB_L);
            gload_lds16(sK + (size_t)(2 * w4 + 1) * 512 + lane * 8, Gb + (2 * w4 + 1) * CHB_L);
            gload_lds16(sV + (size_t)(2 * w4) * 512 + lane * 8,     Gb + 8192 + (2 * w4) * CHB_L);
            gload_lds16(sV + (size_t)(2 * w4 + 1) * 512 + lane * 8, Gb + 8192 + (2 * w4 + 1) * CHB_L);
        }
    }

    // ---- epilogue: merge the two key-halves via LDS (R11-verified math) ----
    __syncthreads();   // all epochs done; staging LDS dead
    float* Xo  = (float*)smem;             // [128 rows][64 cols] = 32 KB
    float* Xml = (float*)(smem + 32768);   // [128][2] (m, l) = 1 KB

    if (grp == 1) {
#pragma unroll
        for (int r = 0; r < 16; ++r) {
            int row = w4 * 32 + (r & 3) + 8 * (r >> 2) + 4 * h;
            Xo[row * 64 + l31]      = o0[r];
            Xo[row * 64 + 32 + l31] = o1[r];
        }
        Xml[(w4 * 32 + l31) * 2 + 0] = m_run;   // both h-lanes write same — benign
        Xml[(w4 * 32 + l31) * 2 + 1] = l_run;
    }
    __syncthreads();
    if (grp == 0) {
        float* ob = out + ((size_t)bh * SLEN + q0 + w4 * 32) * DH;
#pragma unroll
        for (int r = 0; r < 16; ++r) {
            int R = (r & 3) + 8 * (r >> 2) + 4 * h;
            float m0 = __shfl(m_run, R);
            float l0 = __shfl(l_run, R);
            float m1 = Xml[(w4 * 32 + R) * 2 + 0];
            float l1 = Xml[(w4 * 32 + R) * 2 + 1];
            float M  = fmaxf(m0, m1);
            float a0 = exp2f(m0 - M), a1 = exp2f(m1 - M);
            float inv = 1.f / (l0 * a0 + l1 * a1);
            ob[R * DH + l31]      = (o0[r] * a0 + Xo[(w4 * 32 + R) * 64 + l31]      * a1) * inv;
            ob[R * DH + 32 + l31] = (o1[r] * a0 + Xo[(w4 * 32 + R) * 64 + 32 + l31] * a1) * inv;
        }
    }
}

// ---- legacy fallback (round-1 kernel) if ws is too small for the prepass ----
#define LDT 72
__global__ __launch_bounds__(256) void attn_mask_flags(
    const float* __restrict__ mask, int* __restrict__ flags)
{
    const int kt = blockIdx.x, qt = blockIdx.y;
    const int t = threadIdx.x;
    float acc = 0.f;
#pragma unroll
    for (int i = 0; i < 4; ++i) {
        int f = i * 256 + t;
        int row = f >> 4, c4 = (f & 15) * 4;
        const float4 v = *(const float4*)(mask + (size_t)(qt * BR + row) * SLEN + kt * BC + c4);
        acc = fmaxf(acc, fmaxf(fmaxf(fabsf(v.x), fabsf(v.y)), fmaxf(fabsf(v.z), fabsf(v.w))));
    }
    unsigned long long any = __ballot(acc != 0.f);
    __shared__ int wany[4];
    if ((t & 63) == 0) wany[t >> 6] = (any != 0ull) ? 1 : 0;
    __syncthreads();
    if (t == 0) flags[qt * NKT + kt] = wany[0] | wany[1] | wany[2] | wany[3];
}

__global__ __launch_bounds__(256) void attn_fwd(
    const float* __restrict__ q, const float* __restrict__ kv,
    const float* __restrict__ mask, const int* __restrict__ flags,
    float* __restrict__ out)
{
    __shared__ __align__(16) bf16 Kl[BC * LDT];
    __shared__ __align__(16) bf16 Vt[DH * LDT];
    __shared__ __align__(16) bf16 Pl[BR * LDT];

    const int qt = blockIdx.x;
    const int bh = blockIdx.y;
    const int q0 = qt * BR;
    const int t = threadIdx.x;
    const int wave = t >> 6, lane = t & 63;
    const int ln16 = lane & 15, quad = lane >> 4;

    const float qscale = 0.125f * LOG2E;
    bf16x8 aq[2];
    {
        const float* qrow = q + ((size_t)bh * SLEN + q0 + wave * 16 + ln16) * DH;
#pragma unroll
        for (int kc = 0; kc < 2; ++kc) {
            float4 f0 = *(const float4*)(qrow + kc * 32 + quad * 8);
            float4 f1 = *(const float4*)(qrow + kc * 32 + quad * 8 + 4);
            bf16x8 a;
            a[0] = (bf16)(f0.x * qscale); a[1] = (bf16)(f0.y * qscale);
            a[2] = (bf16)(f0.z * qscale); a[3] = (bf16)(f0.w * qscale);
            a[4] = (bf16)(f1.x * qscale); a[5] = (bf16)(f1.y * qscale);
            a[6] = (bf16)(f1.z * qscale); a[7] = (bf16)(f1.w * qscale);
            aq[kc] = a;
        }
    }

    floatx4 o[4];
#pragma unroll
    for (int dt = 0; dt < 4; ++dt) o[dt] = (floatx4){0.f, 0.f, 0.f, 0.f};
    float m_run[4], l_run[4];
#pragma unroll
    for (int r = 0; r < 4; ++r) { m_run[r] = -3.0e38f; l_run[r] = 0.f; }

    const float* kvb = kv + (size_t)bh * SLEN * DH;

    for (int kt = 0; kt < NKT; ++kt) {
        float4 st[4];
        const float* kvt = kvb + (size_t)kt * BC * DH;
#pragma unroll
        for (int i = 0; i < 4; ++i) {
            int f = i * 256 + t;
            st[i] = *(const float4*)(kvt + (size_t)f * 4);
        }
        __syncthreads();
#pragma unroll
        for (int i = 0; i < 4; ++i) {
            int f = i * 256 + t;
            int key = f >> 4, d4 = (f & 15) * 4;
            bf16 b0 = (bf16)st[i].x, b1 = (bf16)st[i].y, b2 = (bf16)st[i].z, b3 = (bf16)st[i].w;
            *(bf16x4*)&Kl[key * LDT + d4] = (bf16x4){b0, b1, b2, b3};
            Vt[(d4 + 0) * LDT + key] = b0;
            Vt[(d4 + 1) * LDT + key] = b1;
            Vt[(d4 + 2) * LDT + key] = b2;
            Vt[(d4 + 3) * LDT + key] = b3;
        }
        __syncthreads();

        floatx4 s[4];
#pragma unroll
        for (int nt = 0; nt < 4; ++nt) {
            s[nt] = (floatx4){0.f, 0.f, 0.f, 0.f};
#pragma unroll
            for (int kc = 0; kc < 2; ++kc) {
                bf16x8 bk = *(const bf16x8*)&Kl[(ln16 + 16 * nt) * LDT + kc * 32 + quad * 8];
                s[nt] = __builtin_amdgcn_mfma_f32_16x16x32_bf16(aq[kc], bk, s[nt], 0, 0, 0);
            }
        }

        if (!flags || flags[qt * NKT + kt]) {
            const float* mrow = mask + (size_t)(q0 + quad * 4) * SLEN + kt * BC + ln16;
#pragma unroll
            for (int r = 0; r < 4; ++r)
#pragma unroll
                for (int nt = 0; nt < 4; ++nt)
                    s[nt][r] += mrow[(size_t)r * SLEN + nt * 16] * LOG2E;
        }

#pragma unroll
        for (int r = 0; r < 4; ++r) {
            float mx = fmaxf(fmaxf(s[0][r], s[1][r]), fmaxf(s[2][r], s[3][r]));
            mx = fmaxf(mx, __shfl_xor(mx, 1));
            mx = fmaxf(mx, __shfl_xor(mx, 2));
            mx = fmaxf(mx, __shfl_xor(mx, 4));
            mx = fmaxf(mx, __shfl_xor(mx, 8));
            float mnew = fmaxf(m_run[r], mx);
            float alpha = exp2f(m_run[r] - mnew);
            m_run[r] = mnew;
            float rs = 0.f;
#pragma unroll
            for (int nt = 0; nt < 4; ++nt) {
                float p = exp2f(s[nt][r] - mnew);
                s[nt][r] = p;
                rs += p;
            }
            rs += __shfl_xor(rs, 1);
            rs += __shfl_xor(rs, 2);
            rs += __shfl_xor(rs, 4);
            rs += __shfl_xor(rs, 8);
            l_run[r] = l_run[r] * alpha + rs;
#pragma unroll
            for (int dt = 0; dt < 4; ++dt) o[dt][r] *= alpha;
        }

#pragma unroll
        for (int nt = 0; nt < 4; ++nt)
#pragma unroll
            for (int r = 0; r < 4; ++r)
                Pl[(wave * 16 + quad * 4 + r) * LDT + ln16 + 16 * nt] = (bf16)s[nt][r];

#pragma unroll
        for (int kc2 = 0; kc2 < 2; ++kc2) {
            bf16x8 pfr = *(const bf16x8*)&Pl[(wave * 16 + ln16) * LDT + kc2 * 32 + quad * 8];
#pragma unroll
            for (int dt = 0; dt < 4; ++dt) {
                bf16x8 vfr = *(const bf16x8*)&Vt[(ln16 + 16 * dt) * LDT + kc2 * 32 + quad * 8];
                o[dt] = __builtin_amdgcn_mfma_f32_16x16x32_bf16(pfr, vfr, o[dt], 0, 0, 0);
            }
        }
    }

#pragma unroll
    for (int r = 0; r < 4; ++r) {
        float inv = 1.0f / l_run[r];
        int qrow = q0 + wave * 16 + quad * 4 + r;
        float* orow = out + ((size_t)bh * SLEN + qrow) * DH;
#pragma unroll
        for (int dt = 0; dt < 4; ++dt)
            orow[ln16 + 16 * dt] = o[dt][r] * inv;
    }
}

extern "C" void kernel_launch(void* const* d_in, const int* in_sizes, int n_in,
                              void* d_out, int out_size, void* d_ws, size_t ws_size,
                              hipStream_t stream)
{
    const float* q    = (const float*)d_in[0];
    const float* kv   = (const float*)d_in[1];
    const float* mask = (const float*)d_in[2];
    float* out = (float*)d_out;

    const size_t kvKoff = 4096;                                   // flags: 32*32*4
    const size_t kvToff = kvKoff + (size_t)BH_N * NKT * IMGE_G * 2;
    const size_t need   = kvToff + (size_t)BH_N * NKT * IMGE_G * 2;

    if (ws_size >= need) {
        int*  flags = (int*)d_ws;
        bf16* kvK   = (bf16*)((char*)d_ws + kvKoff);
        bf16* kvT   = (bf16*)((char*)d_ws + kvToff);
        kv_prep<<<dim3(NKT, BH_N), 256, 0, stream>>>(kv, mask, kvK, kvT, flags);
        attn_fwd12<<<dim3(BH_N, SLEN / 128), 512, 0, stream>>>(q, mask, flags, kvK, kvT, out);
    } else {
        int* flags = nullptr;
        if (ws_size >= (size_t)NQT * NKT * sizeof(int)) {
            flags = (int*)d_ws;
            attn_mask_flags<<<dim3(NKT, NQT), 256, 0, stream>>>(mask, flags);
        }
        attn_fwd<<<dim3(NQT, BH_N), 256, 0, stream>>>(q, kv, mask, flags, out);
    }
}

// Round 13
// 142.431 us; speedup vs baseline: 1.2175x; 1.2175x over previous
//
#include <hip/hip_runtime.h>
#include <hip/hip_bf16.h>
#include <stdint.h>

// Flash attention B=4,H=8,S=2048,D=64 fp32 io, bf16 MFMA compute.
// Round 13: R8 verbatim (best: 80us attn, verified online softmax) with ONE
// change: exp2f -> __builtin_amdgcn_exp2f (raw v_exp_f32, no OCML fixup
// path). Args are <= 0 (max subtracted) so the native op is exact enough.

typedef __bf16 bf16;
typedef __attribute__((ext_vector_type(8))) __bf16 bf16x8;
typedef __attribute__((ext_vector_type(4))) __bf16 bf16x4;
typedef __attribute__((ext_vector_type(4))) float floatx4;

#define SLEN 2048
#define DH   64
#define BR   64
#define BC   64
#define NKT  (SLEN / BC)      // 32 64-key tiles
#define NEP  (NKT / 2)        // 16 epochs of 128 keys
#define NQT  (SLEN / BR)
#define BH_N 32
#define LOG2E 1.44269504088896341f

#define CHB_L  1024           // LDS chunk stride (8 rows x 128B, no pad)
#define IMGB_L 8192           // bytes per K or V image (8 chunks)
#define IMGE_G 4096           // bf16 elements per image in global (8192 B)
#define BUF2   (4 * IMGB_L)   // K0,V0,K1,V1 per epoch buffer (32 KB)

#define AS1 __attribute__((address_space(1)))
#define AS3 __attribute__((address_space(3)))

static __device__ inline void gload_lds16(const void* g, void* l) {
    __builtin_amdgcn_global_load_lds((const AS1 uint32_t*)g, (AS3 uint32_t*)l, 16, 0, 0);
}

static __device__ inline float fexp2(float x) {
    return __builtin_amdgcn_exp2f(x);   // raw v_exp_f32
}

static_assert(BH_N == NQT, "prep kernel folds bh and qt onto one grid axis");

// logical key l (0..63) -> physical key within 64-key tile
static __device__ inline int phys_key(int l) {
    int h = l >> 5, l5 = l & 31, q = l5 >> 3, j = l5 & 7;
    return 32 * h + (j < 4 ? 4 * q + j : 16 + 4 * q + (j - 4));
}

// ---- prepass (R8 verbatim): kv -> swizzled K/V LDS-images + mask flags ----
// granule (chunk c, pos p, row rl): content granule g = (p - rl - 4*(c&1)) & 7
__global__ __launch_bounds__(256) void kv_prep(
    const float* __restrict__ kv, const float* __restrict__ mask,
    bf16* __restrict__ kvK, bf16* __restrict__ kvT, int* __restrict__ flags)
{
    __shared__ bf16 Tl[64 * 72];
    __shared__ int wany[4];
    const int kt = blockIdx.x, z = blockIdx.y;   // z = bh for kv, z = qt for mask
    const int t = threadIdx.x;

    float acc = 0.f;
#pragma unroll
    for (int i = 0; i < 4; ++i) {
        int f = i * 256 + t;
        int row = f >> 4, c4 = (f & 15) * 4;
        const float4 v = *(const float4*)(mask + (size_t)(z * BR + row) * SLEN + kt * BC + c4);
        acc = fmaxf(acc, fmaxf(fmaxf(fabsf(v.x), fabsf(v.y)), fmaxf(fabsf(v.z), fabsf(v.w))));
    }
    unsigned long long any = __ballot(acc != 0.f);
    if ((t & 63) == 0) wany[t >> 6] = (any != 0ull) ? 1 : 0;

    const float* src = kv + ((size_t)z * SLEN + kt * BC) * DH;
#pragma unroll
    for (int i = 0; i < 4; ++i) {
        int f = i * 256 + t;
        int key = f >> 4, d4 = (f & 15) * 4;
        float4 v = *(const float4*)(src + (size_t)key * DH + d4);
        bf16x4 b; b[0] = (bf16)v.x; b[1] = (bf16)v.y; b[2] = (bf16)v.z; b[3] = (bf16)v.w;
        *(bf16x4*)&Tl[key * 72 + d4] = b;
    }
    __syncthreads();
    if (t == 0) flags[z * NKT + kt] = wany[0] | wany[1] | wany[2] | wany[3];

    // K image
    bf16* outK = kvK + ((size_t)z * NKT + kt) * IMGE_G;
#pragma unroll
    for (int i = 0; i < 2; ++i) {
        int G = i * 256 + t;
        int c = G >> 6, L = G & 63, rl = L >> 3, p = L & 7;
        int g = (p - rl - 4 * (c & 1)) & 7, key = 8 * c + rl;
        bf16x8 w = *(const bf16x8*)&Tl[key * 72 + g * 8];
        *(bf16x8*)(outK + (size_t)G * 8) = w;
    }
    // V image: rows = d, content = logical keys 8g..8g+7 gathered via phys_key
    bf16* outV = kvT + ((size_t)z * NKT + kt) * IMGE_G;
#pragma unroll
    for (int i = 0; i < 2; ++i) {
        int G = i * 256 + t;
        int c = G >> 6, L = G & 63, dl = L >> 3, p = L & 7;
        int g = (p - dl - 4 * (c & 1)) & 7, d = 8 * c + dl;
        bf16x8 w;
#pragma unroll
        for (int j = 0; j < 8; ++j)
            w[j] = Tl[phys_key(8 * g + j) * 72 + d];
        *(bf16x8*)(outV + (size_t)G * 8) = w;
    }
}

// ---- main fused attention: R8 structure, raw v_exp_f32 softmax ----
__global__ __launch_bounds__(512) void attn_fwd13(
    const float* __restrict__ q, const float* __restrict__ mask,
    const int* __restrict__ flags,
    const bf16* __restrict__ kvK, const bf16* __restrict__ kvT,
    float* __restrict__ out)
{
    __shared__ __align__(16) char smem[2 * BUF2];   // 64 KiB

    const int bh = blockIdx.x;
    const int qt = blockIdx.y;          // 128-row q tile
    const int q0 = qt * 128;
    const int t = threadIdx.x;
    const int wave = t >> 6, lane = t & 63;   // wave in [0,8)
    const int ln16 = lane & 15, quad = lane >> 4;
    const int ln8 = ln16 & 7, hb = ln16 >> 3;

    // Q B-fragments (scale folded): B[k=kc*32+quad*8+j][n=qrow=ln16]
    const float qscale = 0.125f * LOG2E;
    bf16x8 aq[2];
    {
        const float* qrow = q + ((size_t)bh * SLEN + q0 + wave * 16 + ln16) * DH;
#pragma unroll
        for (int kc = 0; kc < 2; ++kc) {
            float4 f0 = *(const float4*)(qrow + kc * 32 + quad * 8);
            float4 f1 = *(const float4*)(qrow + kc * 32 + quad * 8 + 4);
            bf16x8 a;
            a[0] = (bf16)(f0.x * qscale); a[1] = (bf16)(f0.y * qscale);
            a[2] = (bf16)(f0.z * qscale); a[3] = (bf16)(f0.w * qscale);
            a[4] = (bf16)(f1.x * qscale); a[5] = (bf16)(f1.y * qscale);
            a[6] = (bf16)(f1.z * qscale); a[7] = (bf16)(f1.w * qscale);
            aq[kc] = a;
        }
    }

    // flag bitmask for this wave's 64-row flag tile (bit = 64-key tile kt)
    const int fqt = qt * 2 + (wave >> 2);
    unsigned fmask;
    {
        int ld = (lane < 32) ? flags[fqt * NKT + lane] : 0;
        fmask = (unsigned)__ballot(ld != 0);
    }

    // conflict-swizzled read offsets: slot = (quad + kc*4 + ln8 + 4*hb) & 7
    const int kbase0 = hb * CHB_L + ln8 * 128 + (((quad + ln8 + 4 * hb) & 7) << 4);
    const int kbase1 = hb * CHB_L + ln8 * 128 + (((quad + 4 + ln8 + 4 * hb) & 7) << 4);

    floatx4 o[4];
#pragma unroll
    for (int dt = 0; dt < 4; ++dt) o[dt] = (floatx4){0.f, 0.f, 0.f, 0.f};
    float m_run = -3.0e38f, l_run = 0.f;

    const bf16* kvKb = kvK + (size_t)bh * NKT * IMGE_G;
    const bf16* kvTb = kvT + (size_t)bh * NKT * IMGE_G;

    // prologue: stage tiles 0,1 into buffer 0 (each wave: chunk `wave` of 4 images)
    {
        char* B0 = smem;
        gload_lds16(kvKb + (size_t)wave * 512 + lane * 8,           B0 +             wave * CHB_L);
        gload_lds16(kvTb + (size_t)wave * 512 + lane * 8,           B0 + IMGB_L +    wave * CHB_L);
        gload_lds16(kvKb + IMGE_G + (size_t)wave * 512 + lane * 8,  B0 + 2*IMGB_L +  wave * CHB_L);
        gload_lds16(kvTb + IMGE_G + (size_t)wave * 512 + lane * 8,  B0 + 3*IMGB_L +  wave * CHB_L);
    }

    for (int e = 0; e < NEP; ++e) {
        __syncthreads();   // drains vmcnt -> buf[e&1] ready; prev compute done

        if (e + 1 < NEP) {   // prefetch next epoch's 2 tiles into the other buffer
            char* Bn = smem + ((e + 1) & 1) * BUF2;
            const bf16* gK0 = kvKb + (size_t)(2 * e + 2) * IMGE_G;
            const bf16* gV0 = kvTb + (size_t)(2 * e + 2) * IMGE_G;
            gload_lds16(gK0 + (size_t)wave * 512 + lane * 8,          Bn +            wave * CHB_L);
            gload_lds16(gV0 + (size_t)wave * 512 + lane * 8,          Bn + IMGB_L +   wave * CHB_L);
            gload_lds16(gK0 + IMGE_G + (size_t)wave * 512 + lane * 8, Bn + 2*IMGB_L + wave * CHB_L);
            gload_lds16(gV0 + IMGE_G + (size_t)wave * 512 + lane * 8, Bn + 3*IMGB_L + wave * CHB_L);
        }

        const char* B  = smem + (e & 1) * BUF2;
        const char* K0 = B;
        const char* V0 = B + IMGB_L;
        const char* K1 = B + 2 * IMGB_L;
        const char* V1 = B + 3 * IMGB_L;

        // S^T = K * Q^T for both sub-tiles (independent chains)
        floatx4 s0[4], s1[4];
#pragma unroll
        for (int nt = 0; nt < 4; ++nt) {
            bf16x8 a0 = *(const bf16x8*)(K0 + nt * 2048 + kbase0);
            bf16x8 a1 = *(const bf16x8*)(K0 + nt * 2048 + kbase1);
            floatx4 acc = (floatx4){0.f, 0.f, 0.f, 0.f};
            acc = __builtin_amdgcn_mfma_f32_16x16x32_bf16(a0, aq[0], acc, 0, 0, 0);
            acc = __builtin_amdgcn_mfma_f32_16x16x32_bf16(a1, aq[1], acc, 0, 0, 0);
            s0[nt] = acc;
        }
#pragma unroll
        for (int nt = 0; nt < 4; ++nt) {
            bf16x8 a0 = *(const bf16x8*)(K1 + nt * 2048 + kbase0);
            bf16x8 a1 = *(const bf16x8*)(K1 + nt * 2048 + kbase1);
            floatx4 acc = (floatx4){0.f, 0.f, 0.f, 0.f};
            acc = __builtin_amdgcn_mfma_f32_16x16x32_bf16(a0, aq[0], acc, 0, 0, 0);
            acc = __builtin_amdgcn_mfma_f32_16x16x32_bf16(a1, aq[1], acc, 0, 0, 0);
            s1[nt] = acc;
        }

        // mask add per 64-key sub-tile (usually skipped)
        if (fmask & (1u << (2 * e))) {
            const float* mrow = mask + (size_t)(q0 + wave * 16 + ln16) * SLEN + (2 * e) * BC;
#pragma unroll
            for (int nt = 0; nt < 4; ++nt) {
                float4 mv = *(const float4*)(mrow + 16 * nt + quad * 4);
                s0[nt][0] += mv.x * LOG2E; s0[nt][1] += mv.y * LOG2E;
                s0[nt][2] += mv.z * LOG2E; s0[nt][3] += mv.w * LOG2E;
            }
        }
        if (fmask & (1u << (2 * e + 1))) {
            const float* mrow = mask + (size_t)(q0 + wave * 16 + ln16) * SLEN + (2 * e + 1) * BC;
#pragma unroll
            for (int nt = 0; nt < 4; ++nt) {
                float4 mv = *(const float4*)(mrow + 16 * nt + quad * 4);
                s1[nt][0] += mv.x * LOG2E; s1[nt][1] += mv.y * LOG2E;
                s1[nt][2] += mv.z * LOG2E; s1[nt][3] += mv.w * LOG2E;
            }
        }

        // online softmax over 128 keys: one q-row per lane (row = ln16)
        float tm0 = s0[0][0], tm1 = s1[0][0];
#pragma unroll
        for (int nt = 0; nt < 4; ++nt)
#pragma unroll
            for (int r = 0; r < 4; ++r) {
                tm0 = fmaxf(tm0, s0[nt][r]);
                tm1 = fmaxf(tm1, s1[nt][r]);
            }
        float tmax = fmaxf(tm0, tm1);
        tmax = fmaxf(tmax, __shfl_xor(tmax, 16));
        tmax = fmaxf(tmax, __shfl_xor(tmax, 32));
        float mnew = fmaxf(m_run, tmax);
        unsigned long long grew = __ballot(mnew > m_run);
        float alpha = fexp2(m_run - mnew);
        m_run = mnew;

        float rs = 0.f;
        bf16x8 pf00, pf01, pf10, pf11;
#pragma unroll
        for (int r = 0; r < 4; ++r) {
            float a0 = fexp2(s0[0][r] - mnew);
            float a1 = fexp2(s0[1][r] - mnew);
            float a2 = fexp2(s0[2][r] - mnew);
            float a3 = fexp2(s0[3][r] - mnew);
            float b0 = fexp2(s1[0][r] - mnew);
            float b1 = fexp2(s1[1][r] - mnew);
            float b2 = fexp2(s1[2][r] - mnew);
            float b3 = fexp2(s1[3][r] - mnew);
            rs += ((a0 + a1) + (a2 + a3)) + ((b0 + b1) + (b2 + b3));
            pf00[r] = (bf16)a0; pf00[4 + r] = (bf16)a1;
            pf01[r] = (bf16)a2; pf01[4 + r] = (bf16)a3;
            pf10[r] = (bf16)b0; pf10[4 + r] = (bf16)b1;
            pf11[r] = (bf16)b2; pf11[4 + r] = (bf16)b3;
        }
        rs += __shfl_xor(rs, 16);
        rs += __shfl_xor(rs, 32);

        if (grew) {
            l_run = l_run * alpha + rs;
            float a0 = __shfl(alpha, quad * 4 + 0);
            float a1 = __shfl(alpha, quad * 4 + 1);
            float a2 = __shfl(alpha, quad * 4 + 2);
            float a3 = __shfl(alpha, quad * 4 + 3);
#pragma unroll
            for (int dt = 0; dt < 4; ++dt) {
                o[dt][0] *= a0; o[dt][1] *= a1; o[dt][2] *= a2; o[dt][3] *= a3;
            }
        } else {
            l_run += rs;
        }

        // O += P V for both sub-tiles
#pragma unroll
        for (int dt = 0; dt < 4; ++dt) {
            bf16x8 v0 = *(const bf16x8*)(V0 + dt * 2048 + kbase0);
            bf16x8 v1 = *(const bf16x8*)(V0 + dt * 2048 + kbase1);
            o[dt] = __builtin_amdgcn_mfma_f32_16x16x32_bf16(pf00, v0, o[dt], 0, 0, 0);
            o[dt] = __builtin_amdgcn_mfma_f32_16x16x32_bf16(pf01, v1, o[dt], 0, 0, 0);
        }
#pragma unroll
        for (int dt = 0; dt < 4; ++dt) {
            bf16x8 v0 = *(const bf16x8*)(V1 + dt * 2048 + kbase0);
            bf16x8 v1 = *(const bf16x8*)(V1 + dt * 2048 + kbase1);
            o[dt] = __builtin_amdgcn_mfma_f32_16x16x32_bf16(pf10, v0, o[dt], 0, 0, 0);
            o[dt] = __builtin_amdgcn_mfma_f32_16x16x32_bf16(pf11, v1, o[dt], 0, 0, 0);
        }
    }

    // epilogue: O rows = quad*4+r, cols = ln16+16dt; l lives at lane quad*4+r
    float l0 = __shfl(l_run, quad * 4 + 0);
    float l1 = __shfl(l_run, quad * 4 + 1);
    float l2 = __shfl(l_run, quad * 4 + 2);
    float l3 = __shfl(l_run, quad * 4 + 3);
    float i0 = 1.f / l0, i1 = 1.f / l1, i2 = 1.f / l2, i3 = 1.f / l3;
    float* ob = out + ((size_t)bh * SLEN + q0 + wave * 16) * DH;
#pragma unroll
    for (int dt = 0; dt < 4; ++dt) {
        int col = ln16 + 16 * dt;
        ob[(quad * 4 + 0) * DH + col] = o[dt][0] * i0;
        ob[(quad * 4 + 1) * DH + col] = o[dt][1] * i1;
        ob[(quad * 4 + 2) * DH + col] = o[dt][2] * i2;
        ob[(quad * 4 + 3) * DH + col] = o[dt][3] * i3;
    }
}

// ---- legacy fallback (round-1 kernel) if ws is too small for the prepass ----
#define LDT 72
__global__ __launch_bounds__(256) void attn_mask_flags(
    const float* __restrict__ mask, int* __restrict__ flags)
{
    const int kt = blockIdx.x, qt = blockIdx.y;
    const int t = threadIdx.x;
    float acc = 0.f;
#pragma unroll
    for (int i = 0; i < 4; ++i) {
        int f = i * 256 + t;
        int row = f >> 4, c4 = (f & 15) * 4;
        const float4 v = *(const float4*)(mask + (size_t)(qt * BR + row) * SLEN + kt * BC + c4);
        acc = fmaxf(acc, fmaxf(fmaxf(fabsf(v.x), fabsf(v.y)), fmaxf(fabsf(v.z), fabsf(v.w))));
    }
    unsigned long long any = __ballot(acc != 0.f);
    __shared__ int wany[4];
    if ((t & 63) == 0) wany[t >> 6] = (any != 0ull) ? 1 : 0;
    __syncthreads();
    if (t == 0) flags[qt * NKT + kt] = wany[0] | wany[1] | wany[2] | wany[3];
}

__global__ __launch_bounds__(256) void attn_fwd(
    const float* __restrict__ q, const float* __restrict__ kv,
    const float* __restrict__ mask, const int* __restrict__ flags,
    float* __restrict__ out)
{
    __shared__ __align__(16) bf16 Kl[BC * LDT];
    __shared__ __align__(16) bf16 Vt[DH * LDT];
    __shared__ __align__(16) bf16 Pl[BR * LDT];

    const int qt = blockIdx.x;
    const int bh = blockIdx.y;
    const int q0 = qt * BR;
    const int t = threadIdx.x;
    const int wave = t >> 6, lane = t & 63;
    const int ln16 = lane & 15, quad = lane >> 4;

    const float qscale = 0.125f * LOG2E;
    bf16x8 aq[2];
    {
        const float* qrow = q + ((size_t)bh * SLEN + q0 + wave * 16 + ln16) * DH;
#pragma unroll
        for (int kc = 0; kc < 2; ++kc) {
            float4 f0 = *(const float4*)(qrow + kc * 32 + quad * 8);
            float4 f1 = *(const float4*)(qrow + kc * 32 + quad * 8 + 4);
            bf16x8 a;
            a[0] = (bf16)(f0.x * qscale); a[1] = (bf16)(f0.y * qscale);
            a[2] = (bf16)(f0.z * qscale); a[3] = (bf16)(f0.w * qscale);
            a[4] = (bf16)(f1.x * qscale); a[5] = (bf16)(f1.y * qscale);
            a[6] = (bf16)(f1.z * qscale); a[7] = (bf16)(f1.w * qscale);
            aq[kc] = a;
        }
    }

    floatx4 o[4];
#pragma unroll
    for (int dt = 0; dt < 4; ++dt) o[dt] = (floatx4){0.f, 0.f, 0.f, 0.f};
    float m_run[4], l_run[4];
#pragma unroll
    for (int r = 0; r < 4; ++r) { m_run[r] = -3.0e38f; l_run[r] = 0.f; }

    const float* kvb = kv + (size_t)bh * SLEN * DH;

    for (int kt = 0; kt < NKT; ++kt) {
        float4 st[4];
        const float* kvt = kvb + (size_t)kt * BC * DH;
#pragma unroll
        for (int i = 0; i < 4; ++i) {
            int f = i * 256 + t;
            st[i] = *(const float4*)(kvt + (size_t)f * 4);
        }
        __syncthreads();
#pragma unroll
        for (int i = 0; i < 4; ++i) {
            int f = i * 256 + t;
            int key = f >> 4, d4 = (f & 15) * 4;
            bf16 b0 = (bf16)st[i].x, b1 = (bf16)st[i].y, b2 = (bf16)st[i].z, b3 = (bf16)st[i].w;
            *(bf16x4*)&Kl[key * LDT + d4] = (bf16x4){b0, b1, b2, b3};
            Vt[(d4 + 0) * LDT + key] = b0;
            Vt[(d4 + 1) * LDT + key] = b1;
            Vt[(d4 + 2) * LDT + key] = b2;
            Vt[(d4 + 3) * LDT + key] = b3;
        }
        __syncthreads();

        floatx4 s[4];
#pragma unroll
        for (int nt = 0; nt < 4; ++nt) {
            s[nt] = (floatx4){0.f, 0.f, 0.f, 0.f};
#pragma unroll
            for (int kc = 0; kc < 2; ++kc) {
                bf16x8 bk = *(const bf16x8*)&Kl[(ln16 + 16 * nt) * LDT + kc * 32 + quad * 8];
                s[nt] = __builtin_amdgcn_mfma_f32_16x16x32_bf16(aq[kc], bk, s[nt], 0, 0, 0);
            }
        }

        if (!flags || flags[qt * NKT + kt]) {
            const float* mrow = mask + (size_t)(q0 + quad * 4) * SLEN + kt * BC + ln16;
#pragma unroll
            for (int r = 0; r < 4; ++r)
#pragma unroll
                for (int nt = 0; nt < 4; ++nt)
                    s[nt][r] += mrow[(size_t)r * SLEN + nt * 16] * LOG2E;
        }

#pragma unroll
        for (int r = 0; r < 4; ++r) {
            float mx = fmaxf(fmaxf(s[0][r], s[1][r]), fmaxf(s[2][r], s[3][r]));
            mx = fmaxf(mx, __shfl_xor(mx, 1));
            mx = fmaxf(mx, __shfl_xor(mx, 2));
            mx = fmaxf(mx, __shfl_xor(mx, 4));
            mx = fmaxf(mx, __shfl_xor(mx, 8));
            float mnew = fmaxf(m_run[r], mx);
            float alpha = exp2f(m_run[r] - mnew);
            m_run[r] = mnew;
            float rs = 0.f;
#pragma unroll
            for (int nt = 0; nt < 4; ++nt) {
                float p = exp2f(s[nt][r] - mnew);
                s[nt][r] = p;
                rs += p;
            }
            rs += __shfl_xor(rs, 1);
            rs += __shfl_xor(rs, 2);
            rs += __shfl_xor(rs, 4);
            rs += __shfl_xor(rs, 8);
            l_run[r] = l_run[r] * alpha + rs;
#pragma unroll
            for (int dt = 0; dt < 4; ++dt) o[dt][r] *= alpha;
        }

#pragma unroll
        for (int nt = 0; nt < 4; ++nt)
#pragma unroll
            for (int r = 0; r < 4; ++r)
                Pl[(wave * 16 + quad * 4 + r) * LDT + ln16 + 16 * nt] = (bf16)s[nt][r];

#pragma unroll
        for (int kc2 = 0; kc2 < 2; ++kc2) {
            bf16x8 pfr = *(const bf16x8*)&Pl[(wave * 16 + ln16) * LDT + kc2 * 32 + quad * 8];
#pragma unroll
            for (int dt = 0; dt < 4; ++dt) {
                bf16x8 vfr = *(const bf16x8*)&Vt[(ln16 + 16 * dt) * LDT + kc2 * 32 + quad * 8];
                o[dt] = __builtin_amdgcn_mfma_f32_16x16x32_bf16(pfr, vfr, o[dt], 0, 0, 0);
            }
        }
    }

#pragma unroll
    for (int r = 0; r < 4; ++r) {
        float inv = 1.0f / l_run[r];
        int qrow = q0 + wave * 16 + quad * 4 + r;
        float* orow = out + ((size_t)bh * SLEN + qrow) * DH;
#pragma unroll
        for (int dt = 0; dt < 4; ++dt)
            orow[ln16 + 16 * dt] = o[dt][r] * inv;
    }
}

extern "C" void kernel_launch(void* const* d_in, const int* in_sizes, int n_in,
                              void* d_out, int out_size, void* d_ws, size_t ws_size,
                              hipStream_t stream)
{
    const float* q    = (const float*)d_in[0];
    const float* kv   = (const float*)d_in[1];
    const float* mask = (const float*)d_in[2];
    float* out = (float*)d_out;

    const size_t kvKoff = 4096;                                   // flags: 32*32*4
    const size_t kvToff = kvKoff + (size_t)BH_N * NKT * IMGE_G * 2;
    const size_t need   = kvToff + (size_t)BH_N * NKT * IMGE_G * 2;

    if (ws_size >= need) {
        int*  flags = (int*)d_ws;
        bf16* kvK   = (bf16*)((char*)d_ws + kvKoff);
        bf16* kvT   = (bf16*)((char*)d_ws + kvToff);
        kv_prep<<<dim3(NKT, BH_N), 256, 0, stream>>>(kv, mask, kvK, kvT, flags);
        attn_fwd13<<<dim3(BH_N, SLEN / 128), 512, 0, stream>>>(q, mask, flags, kvK, kvT, out);
    } else {
        int* flags = nullptr;
        if (ws_size >= (size_t)NQT * NKT * sizeof(int)) {
            flags = (int*)d_ws;
            attn_mask_flags<<<dim3(NKT, NQT), 256, 0, stream>>>(mask, flags);
        }
        attn_fwd<<<dim3(NQT, BH_N), 256, 0, stream>>>(q, kv, mask, flags, out);
    }
}